// Round 3
// baseline (78.596 us; speedup 1.0000x reference)
//
#include <hip/hip_runtime.h>
#include <hip/hip_cooperative_groups.h>
#include <math.h>
#include <stdint.h>

namespace cg = cooperative_groups;

// MMCE: sum_{i,j} v_i v_j exp(-|p_i - p_j| / 0.4) / N^2
//   p_i = max softmax prob of row i, v_i = (argmax_i == target_i) - p_i.
// a_i = v_i e^{-p_i/bw}, b_i = v_i e^{+p_i/bw};
// pair term = med3(a_i*b_j, b_i*a_j, 0)  (branch-free |.| decomposition:
// both products share the sign of v_i*v_j; med3 picks min if positive,
// max if negative -- exactly v_i v_j e^{-|p_i-p_j|/bw}).

static constexpr float KBW_INV = 2.5f;           // 1/0.4
static constexpr double FXSCALE = 1073741824.0;  // 2^30 fixed-point

#define TPB 256
#define RPW 4    // rows per wave (phase 1)
#define JBLK 128 // j-rows staged per block (phase 2)
#define IPT 4    // i-rows per thread (phase 2)

__global__ __launch_bounds__(TPB) void mmce_fused(
    const float* __restrict__ inp, const int* __restrict__ tgt,
    float2* __restrict__ AB, unsigned long long* __restrict__ acc,
    unsigned int* __restrict__ counter, float* __restrict__ out,
    int N, int C, int nJB, int nBlocks) {
  const int tid = threadIdx.x;
  const int wv = tid >> 6;
  const int lane = tid & 63;

  if (blockIdx.x == 0 && tid == 0) { *acc = 0ull; *counter = 0u; }

  // ---------------- Phase 1: per-row stats, 4 rows/wave, ILP ----------------
  const int C4 = C >> 2;  // 250 float4 per row
  const int rowbase = blockIdx.x * (4 * RPW) + wv * RPW;

  float4 x[RPW][4];
  #pragma unroll
  for (int r = 0; r < RPW; ++r) {
    const float4* rp =
        reinterpret_cast<const float4*>(inp + (size_t)(rowbase + r) * C);
    #pragma unroll
    for (int w = 0; w < 4; ++w) {
      const int k = lane + w * 64;
      x[r][w] = (k < C4)
                    ? rp[k]
                    : make_float4(-INFINITY, -INFINITY, -INFINITY, -INFINITY);
    }
  }

  float m[RPW];
  int am[RPW];
  #pragma unroll
  for (int r = 0; r < RPW; ++r) {
    m[r] = -INFINITY;
    am[r] = 0x7fffffff;
    #pragma unroll
    for (int w = 0; w < 4; ++w) {
      const int base = (lane + w * 64) * 4;
      const float4 v = x[r][w];
      if (v.x > m[r]) { m[r] = v.x; am[r] = base + 0; }
      if (v.y > m[r]) { m[r] = v.y; am[r] = base + 1; }
      if (v.z > m[r]) { m[r] = v.z; am[r] = base + 2; }
      if (v.w > m[r]) { m[r] = v.w; am[r] = base + 3; }
    }
  }
  // Wave reduce (max, first-index argmax), 4 rows interleaved for ILP.
  #pragma unroll
  for (int off = 32; off; off >>= 1) {
    #pragma unroll
    for (int r = 0; r < RPW; ++r) {
      const float om = __shfl_xor(m[r], off);
      const int oi = __shfl_xor(am[r], off);
      if (om > m[r] || (om == m[r] && oi < am[r])) { m[r] = om; am[r] = oi; }
    }
  }
  // Sum of exp(x - m); -INF padding contributes exp(-inf)=0.
  float s[RPW];
  #pragma unroll
  for (int r = 0; r < RPW; ++r) {
    s[r] = 0.f;
    #pragma unroll
    for (int w = 0; w < 4; ++w) {
      s[r] += __expf(x[r][w].x - m[r]) + __expf(x[r][w].y - m[r]) +
              __expf(x[r][w].z - m[r]) + __expf(x[r][w].w - m[r]);
    }
  }
  #pragma unroll
  for (int off = 32; off; off >>= 1) {
    #pragma unroll
    for (int r = 0; r < RPW; ++r) s[r] += __shfl_xor(s[r], off);
  }
  if (lane == 0) {
    #pragma unroll
    for (int r = 0; r < RPW; ++r) {
      const float p = 1.0f / s[r];
      const float v = ((tgt[rowbase + r] == am[r]) ? 1.0f : 0.0f) - p;
      float2 ab;
      ab.x = v * __expf(-p * KBW_INV);
      ab.y = v * __expf(p * KBW_INV);
      AB[rowbase + r] = ab;
    }
  }

  cg::this_grid().sync();

  // ---------------- Phase 2: pairwise tiles + fused reduction ---------------
  __shared__ float2 sj[JBLK];
  const int bi = blockIdx.x / nJB;
  const int bj = blockIdx.x % nJB;

  if (tid < JBLK) sj[tid] = AB[bj * JBLK + tid];

  float2 abi[IPT];
  #pragma unroll
  for (int u = 0; u < IPT; ++u)
    abi[u] = AB[bi * (TPB * IPT) + u * TPB + tid];
  __syncthreads();

  float facc[IPT];
  #pragma unroll
  for (int u = 0; u < IPT; ++u) facc[u] = 0.f;

  #pragma unroll 8
  for (int t = 0; t < JBLK; ++t) {
    const float aj = sj[t].x;   // uniform t -> LDS broadcast
    const float bj_ = sj[t].y;
    #pragma unroll
    for (int u = 0; u < IPT; ++u) {
      const float xx = abi[u].x * bj_;
      const float yy = abi[u].y * aj;
      facc[u] += __builtin_amdgcn_fmed3f(xx, yy, 0.0f);
    }
  }

  double dacc = (double)((facc[0] + facc[1]) + (facc[2] + facc[3]));
  #pragma unroll
  for (int off = 32; off; off >>= 1) dacc += __shfl_xor(dacc, off);
  __shared__ double wsum[4];
  if ((tid & 63) == 0) wsum[tid >> 6] = dacc;
  __syncthreads();
  if (tid == 0) {
    const double blocksum = (wsum[0] + wsum[1]) + (wsum[2] + wsum[3]);
    const long long fx = __double2ll_rn(blocksum * FXSCALE);
    atomicAdd(acc, (unsigned long long)fx);  // integer adds: deterministic
    __threadfence();
    const unsigned int done = atomicAdd(counter, 1u);
    if (done == (unsigned int)nBlocks - 1u) {
      const unsigned long long total = atomicAdd(acc, 0ull);
      const double sum = (double)(long long)total * (1.0 / FXSCALE);
      out[0] = (float)(sum / ((double)N * (double)N));
    }
  }
}

extern "C" void kernel_launch(void* const* d_in, const int* in_sizes, int n_in,
                              void* d_out, int out_size, void* d_ws, size_t ws_size,
                              hipStream_t stream) {
  const float* inp = (const float*)d_in[0];
  const int* tgt = (const int*)d_in[1];
  int N = in_sizes[1];          // 8192
  int C = in_sizes[0] / N;      // 1000

  float2* AB = (float2*)d_ws;   // N float2
  unsigned long long* acc =
      (unsigned long long*)(((uintptr_t)(AB + N) + 15) & ~(uintptr_t)15);
  unsigned int* counter = (unsigned int*)(acc + 1);
  float* out = (float*)d_out;

  int nBlocks = N / (4 * RPW);          // 512 (also == (N/1024)*(N/128))
  int nJB = N / JBLK;                   // 64

  void* args[] = {&inp, &tgt, &AB, &acc, &counter, &out, &N, &C, &nJB, &nBlocks};
  hipLaunchCooperativeKernel((const void*)mmce_fused, dim3(nBlocks), dim3(TPB),
                             args, 0, stream);
}